// Round 1
// baseline (326.024 us; speedup 1.0000x reference)
//
#include <hip/hip_runtime.h>

typedef __bf16 bf16_t;
typedef __attribute__((ext_vector_type(4))) __bf16 bf16x4;
typedef __attribute__((ext_vector_type(8))) __bf16 bf16x8;
typedef __attribute__((ext_vector_type(4))) float f32x4;

#define MFMA16(a, b, c) __builtin_amdgcn_mfma_f32_16x16x32_bf16((a), (b), (c), 0, 0, 0)
#define AS1 __attribute__((address_space(1)))
#define AS3 __attribute__((address_space(3)))

// Problem: B=8 S=1024 D=768 H=16 Dh=64 OD=1024, M = B*S = 8192
// ws layout (bytes):
static constexpr unsigned XB_OFF = 0u;                          // x bf16: 8192*768*2 = 12,582,912
static constexpr unsigned WT_OFF = 12582912u;                   // wT bf16: 3*1024*768*2 = 4,718,592
static constexpr unsigned Q_OFF  = WT_OFF + 4718592u;           // Q bf16: 8*16*1024*64*2 = 16,777,216
static constexpr unsigned K_OFF  = Q_OFF + 16777216u;
static constexpr unsigned VT_OFF = K_OFF + 16777216u;           // end = 67,633,152

// ---------------- cast kernels ----------------
__global__ __launch_bounds__(256) void cast_x_kernel(const float4* __restrict__ x4,
                                                     bf16x4* __restrict__ out4) {
    unsigned i = blockIdx.x * 256u + threadIdx.x;   // grid sized exactly: 1,572,864 threads
    float4 v = x4[i];
    bf16x4 o;
    o[0] = (bf16_t)v.x; o[1] = (bf16_t)v.y; o[2] = (bf16_t)v.z; o[3] = (bf16_t)v.w;
    out4[i] = o;
}

// w (768,1024) fp32 -> wT (3,1024,768) bf16; q_w scaled by 0.125 (fold attention 1/sqrt(64))
__global__ __launch_bounds__(256) void cast_w_kernel(const float* __restrict__ qw,
                                                     const float* __restrict__ kw,
                                                     const float* __restrict__ vw,
                                                     bf16_t* __restrict__ wT) {
    unsigned t = blockIdx.x * 256u + threadIdx.x;   // 3*1024*192 = 589,824 threads
    unsigned w  = t / 196608u;
    unsigned r  = t % 196608u;
    unsigned n  = r % 1024u;                        // consecutive threads -> consecutive n (coalesced reads)
    unsigned k4 = r / 1024u;                        // 0..191
    const float* src = (w == 0u) ? qw : (w == 1u) ? kw : vw;
    float s = (w == 0u) ? 0.125f : 1.0f;
    bf16x4 o;
#pragma unroll
    for (int i = 0; i < 4; ++i) o[i] = (bf16_t)(src[(k4 * 4u + i) * 1024u + n] * s);
    *(bf16x4*)&wT[(w * 1024u + n) * 768u + k4 * 4u] = o;
}

// ---------------- fused QKV projection GEMM ----------------
// grid (8 nblocks, 64 mblocks, 3 weights), 256 thr. Tile 128x128, BK=32.
__global__ __launch_bounds__(256) void proj_kernel(const bf16_t* __restrict__ xb,
                                                   const bf16_t* __restrict__ wT,
                                                   bf16_t* __restrict__ q,
                                                   bf16_t* __restrict__ k,
                                                   bf16_t* __restrict__ vt) {
    __shared__ __align__(16) bf16_t At[128 * 32];
    __shared__ __align__(16) bf16_t Bt[128 * 32];
    const int nb = blockIdx.x, mb = blockIdx.y, wsel = blockIdx.z;
    const int tid = threadIdx.x;
    const int w = tid >> 6, l = tid & 63;
    const int lo = l & 15, hi = l >> 4;
    const int wr = w >> 1, wc = w & 1;
    const bf16_t* wb = wT + wsel * (1024 * 768);

    f32x4 acc[4][4];
#pragma unroll
    for (int m = 0; m < 4; ++m)
#pragma unroll
        for (int n = 0; n < 4; ++n)
#pragma unroll
            for (int i = 0; i < 4; ++i) acc[m][n][i] = 0.f;

    for (int kt = 0; kt < 24; ++kt) {
#pragma unroll
        for (int i = 0; i < 2; ++i) {
            int be  = w * 1024 + i * 512;            // wave-uniform LDS elem base
            int fl  = be + l * 8;                    // this lane's tile elem
            int row = fl >> 5, col = fl & 31;
            __builtin_amdgcn_global_load_lds(
                (const AS1 void*)(xb + (mb * 128 + row) * 768 + kt * 32 + col),
                (AS3 void*)(At + be), 16, 0, 0);
            __builtin_amdgcn_global_load_lds(
                (const AS1 void*)(wb + (nb * 128 + row) * 768 + kt * 32 + col),
                (AS3 void*)(Bt + be), 16, 0, 0);
        }
        __syncthreads();
        bf16x8 af[4], bfr[4];
#pragma unroll
        for (int m = 0; m < 4; ++m)
            af[m] = *(const bf16x8*)&At[(wr * 64 + m * 16 + lo) * 32 + hi * 8];
#pragma unroll
        for (int n = 0; n < 4; ++n)
            bfr[n] = *(const bf16x8*)&Bt[(wc * 64 + n * 16 + lo) * 32 + hi * 8];
#pragma unroll
        for (int m = 0; m < 4; ++m)
#pragma unroll
            for (int n = 0; n < 4; ++n)
                acc[m][n] = MFMA16(af[m], bfr[n], acc[m][n]);
        __syncthreads();
    }

    // epilogue: scatter to Q[bh][s][d], K[bh][s][d], Vt[bh][d][s] (bf16)
    const int rbase = mb * 128 + wr * 64;
    const int cbase = nb * 128 + wc * 64;
#pragma unroll
    for (int m = 0; m < 4; ++m) {
#pragma unroll
        for (int n = 0; n < 4; ++n) {
#pragma unroll
            for (int r = 0; r < 4; ++r) {
                int mrow = rbase + m * 16 + hi * 4 + r;   // C/D: row=(l>>4)*4+r
                int ncol = cbase + n * 16 + lo;           //      col=l&15
                int bb = mrow >> 10, ss = mrow & 1023;
                int hh = ncol >> 6,  dd = ncol & 63;
                bf16_t v = (bf16_t)acc[m][n][r];
                unsigned head = (unsigned)(bb * 16 + hh) << 16;   // *(1024*64)
                if (wsel == 0)      q[head + (ss << 6) + dd] = v;
                else if (wsel == 1) k[head + (ss << 6) + dd] = v;
                else                vt[head + (dd << 10) + ss] = v;
            }
        }
    }
}

// ---------------- flash attention ----------------
// grid (16 qblocks, 16 heads, 8 batch), 256 thr = 4 waves x 16 q-rows. KV tile = 64.
__global__ __launch_bounds__(256) void attn_kernel(const bf16_t* __restrict__ Q,
                                                   const bf16_t* __restrict__ K,
                                                   const bf16_t* __restrict__ Vt,
                                                   float* __restrict__ out) {
    __shared__ __align__(16) bf16_t Plds[4][16][72];   // per-wave P tile, padded (72)
    const int qb = blockIdx.x, h = blockIdx.y, b = blockIdx.z;
    const int tid = threadIdx.x;
    const int w = tid >> 6, l = tid & 63;
    const int lo = l & 15, hi = l >> 4;
    const unsigned bh = (unsigned)(b * 16 + h) << 16;
    const bf16_t* Qb = Q + bh + (qb * 64 + w * 16) * 64;
    const bf16_t* Kb = K + bh;
    const bf16_t* Vb = Vt + bh;

    // Q A-frags (scale already folded into q_w): row=l&15, k(=d)=hi*8.. contiguous
    bf16x8 qf0 = *(const bf16x8*)&Qb[lo * 64 + hi * 8];
    bf16x8 qf1 = *(const bf16x8*)&Qb[lo * 64 + 32 + hi * 8];

    f32x4 o[4];
#pragma unroll
    for (int dt = 0; dt < 4; ++dt)
#pragma unroll
        for (int i = 0; i < 4; ++i) o[dt][i] = 0.f;
    float m_run[4], l_run[4];
#pragma unroll
    for (int r = 0; r < 4; ++r) { m_run[r] = -__builtin_inff(); l_run[r] = 0.f; }

    for (int kt = 0; kt < 16; ++kt) {
        const int kbase = kt * 64;
        // ---- QK^T ----
        f32x4 sc[4];
#pragma unroll
        for (int c = 0; c < 4; ++c)
#pragma unroll
            for (int i = 0; i < 4; ++i) sc[c][i] = 0.f;
#pragma unroll
        for (int c = 0; c < 4; ++c) {
            const bf16_t* kr = &Kb[(kbase + c * 16 + lo) * 64 + hi * 8];
            bf16x8 kf0 = *(const bf16x8*)kr;
            bf16x8 kf1 = *(const bf16x8*)(kr + 32);
            sc[c] = MFMA16(qf0, kf0, sc[c]);
            sc[c] = MFMA16(qf1, kf1, sc[c]);
        }
        // ---- online softmax (wave-parallel, 16-lane-group xor reduce) ----
        float scale[4];
#pragma unroll
        for (int r = 0; r < 4; ++r) {
            float t = fmaxf(fmaxf(sc[0][r], sc[1][r]), fmaxf(sc[2][r], sc[3][r]));
#pragma unroll
            for (int d = 1; d < 16; d <<= 1) t = fmaxf(t, __shfl_xor(t, d));
            float mnew = fmaxf(m_run[r], t);
            scale[r] = __expf(m_run[r] - mnew);
            float p0 = __expf(sc[0][r] - mnew);
            float p1 = __expf(sc[1][r] - mnew);
            float p2 = __expf(sc[2][r] - mnew);
            float p3 = __expf(sc[3][r] - mnew);
            sc[0][r] = p0; sc[1][r] = p1; sc[2][r] = p2; sc[3][r] = p3;
            float ps = (p0 + p1) + (p2 + p3);
#pragma unroll
            for (int d = 1; d < 16; d <<= 1) ps += __shfl_xor(ps, d);
            l_run[r] = l_run[r] * scale[r] + ps;
            m_run[r] = mnew;
        }
#pragma unroll
        for (int dt = 0; dt < 4; ++dt)
#pragma unroll
            for (int r = 0; r < 4; ++r) o[dt][r] *= scale[r];
        // ---- P -> LDS (C-layout -> A-layout transpose) ----
#pragma unroll
        for (int c = 0; c < 4; ++c)
#pragma unroll
            for (int r = 0; r < 4; ++r)
                Plds[w][hi * 4 + r][c * 16 + lo] = (bf16_t)sc[c][r];
        __syncthreads();
        bf16x8 pf0 = *(const bf16x8*)&Plds[w][lo][hi * 8];
        bf16x8 pf1 = *(const bf16x8*)&Plds[w][lo][32 + hi * 8];
        // ---- PV ----
#pragma unroll
        for (int dt = 0; dt < 4; ++dt) {
            const bf16_t* vr = &Vb[(dt * 16 + lo) * 1024 + kbase + hi * 8];
            bf16x8 vf0 = *(const bf16x8*)vr;
            bf16x8 vf1 = *(const bf16x8*)(vr + 32);
            o[dt] = MFMA16(pf0, vf0, o[dt]);
            o[dt] = MFMA16(pf1, vf1, o[dt]);
        }
        __syncthreads();
    }

    // ---- epilogue: O / l, fp32 out (B,S,1024) ----
    const int qrow = qb * 64 + w * 16 + hi * 4;
#pragma unroll
    for (int r = 0; r < 4; ++r) {
        float inv = 1.f / l_run[r];
#pragma unroll
        for (int dt = 0; dt < 4; ++dt)
            out[(unsigned)(b * 1024 + qrow + r) * 1024u + h * 64 + dt * 16 + lo] = o[dt][r] * inv;
    }
}

extern "C" void kernel_launch(void* const* d_in, const int* in_sizes, int n_in,
                              void* d_out, int out_size, void* d_ws, size_t ws_size,
                              hipStream_t stream) {
    const float* x  = (const float*)d_in[0];
    const float* qw = (const float*)d_in[1];
    const float* kw = (const float*)d_in[2];
    const float* vw = (const float*)d_in[3];
    float* out = (float*)d_out;
    char* ws = (char*)d_ws;
    if (ws_size < 67633152u) return;   // need ~64.5 MB scratch

    bf16_t* xb = (bf16_t*)(ws + XB_OFF);
    bf16_t* wT = (bf16_t*)(ws + WT_OFF);
    bf16_t* Qb = (bf16_t*)(ws + Q_OFF);
    bf16_t* Kb = (bf16_t*)(ws + K_OFF);
    bf16_t* Vt = (bf16_t*)(ws + VT_OFF);

    cast_x_kernel<<<6144, 256, 0, stream>>>((const float4*)x, (bf16x4*)xb);
    cast_w_kernel<<<2304, 256, 0, stream>>>(qw, kw, vw, wT);
    proj_kernel<<<dim3(8, 64, 3), 256, 0, stream>>>(xb, wT, Qb, Kb, Vt);
    attn_kernel<<<dim3(16, 16, 8), 256, 0, stream>>>(Qb, Kb, Vt, out);
}